// Round 2
// 993.692 us; speedup vs baseline: 1.1086x; 1.1086x over previous
//
#include <hip/hip_runtime.h>

#define DD   172
#define TK   516      // 3*D
#define BB   500
#define KK   10
#define MM   1000
#define MSGW 688
#define NR1  1500     // 3*B
#define NR2  15000    // 3*B*K

__device__ __forceinline__ float sigm(float x){ return 1.f / (1.f + expf(-x)); }

// ---------------- generic 32x32 tiled transpose: in[R][C] -> out[C][R] ----
__global__ void k_tr(const float* __restrict__ in, float* __restrict__ out,
                     int R, int C){
  __shared__ float tile[32][33];
  int c0 = blockIdx.x * 32, r0 = blockIdx.y * 32;
  int tx = threadIdx.x, ty = threadIdx.y;        // block 32x8
  for (int i = ty; i < 32; i += 8){
    int r = r0 + i, c = c0 + tx;
    if (r < R && c < C) tile[i][tx] = in[(size_t)r*C + c];
  }
  __syncthreads();
  for (int i = ty; i < 32; i += 8){
    int c = c0 + i, r = r0 + tx;
    if (c < C && r < R) out[(size_t)c*R + r] = tile[tx][i];
  }
}

// ---------------- GRU memory update, 2 msgs/block, transposed weights -----
// msg_node_ids = arange(1000): each block touches only its own rows.
__global__ void k_gru2(const float* __restrict__ msgs, float* memory,
                       const float* __restrict__ WT_ih,   // [MSGW][TK]
                       const float* __restrict__ WT_hh,   // [DD][TK]
                       const float* __restrict__ b_ih, const float* __restrict__ b_hh,
                       const int* __restrict__ ids){
  int t = threadIdx.x;
  int r0 = blockIdx.x * 2;                // 500 blocks
  __shared__ __align__(16) float xT[MSGW][2];
  __shared__ __align__(16) float hT[DD][2];
  int s0 = ids[r0], s1 = ids[r0 + 1];
  for (int c = t; c < MSGW; c += 192){
    xT[c][0] = msgs[(size_t)r0*MSGW + c];
    xT[c][1] = msgs[(size_t)(r0+1)*MSGW + c];
  }
  if (t < DD){
    hT[t][0] = memory[(size_t)s0*DD + t];
    hT[t][1] = memory[(size_t)s1*DD + t];
  }
  __syncthreads();
  if (t < DD){
    float gi00 = b_ih[t],      gi01 = gi00;
    float gi10 = b_ih[DD+t],   gi11 = gi10;
    float gi20 = b_ih[2*DD+t], gi21 = gi20;
    #pragma unroll 4
    for (int c = 0; c < MSGW; c++){
      const float* wr = WT_ih + (size_t)c*TK;
      float w0 = wr[t], w1 = wr[DD+t], w2 = wr[2*DD+t];
      float2 xv = *reinterpret_cast<const float2*>(&xT[c][0]);
      gi00 = fmaf(xv.x, w0, gi00); gi01 = fmaf(xv.y, w0, gi01);
      gi10 = fmaf(xv.x, w1, gi10); gi11 = fmaf(xv.y, w1, gi11);
      gi20 = fmaf(xv.x, w2, gi20); gi21 = fmaf(xv.y, w2, gi21);
    }
    float gh00 = b_hh[t],      gh01 = gh00;
    float gh10 = b_hh[DD+t],   gh11 = gh10;
    float gh20 = b_hh[2*DD+t], gh21 = gh20;
    #pragma unroll 4
    for (int c = 0; c < DD; c++){
      const float* wr = WT_hh + (size_t)c*TK;
      float w0 = wr[t], w1 = wr[DD+t], w2 = wr[2*DD+t];
      float2 hv = *reinterpret_cast<const float2*>(&hT[c][0]);
      gh00 = fmaf(hv.x, w0, gh00); gh01 = fmaf(hv.y, w0, gh01);
      gh10 = fmaf(hv.x, w1, gh10); gh11 = fmaf(hv.y, w1, gh11);
      gh20 = fmaf(hv.x, w2, gh20); gh21 = fmaf(hv.y, w2, gh21);
    }
    {
      float r_ = sigm(gi00 + gh00);
      float z  = sigm(gi10 + gh10);
      float g  = tanhf(gi20 + r_*gh20);
      memory[(size_t)s0*DD + t] = (1.f - z)*g + z*hT[t][0];
    }
    {
      float r_ = sigm(gi01 + gh01);
      float z  = sigm(gi11 + gh11);
      float g  = tanhf(gi21 + r_*gh21);
      memory[(size_t)s1*DD + t] = (1.f - z)*g + z*hT[t][1];
    }
  }
}

// ---------------- lin2 "st" constant: c2_l[j] = b2_l[j] + sum_d cos(b_d) W2_l[2D+d][j]
// consts layout: [0:172) c2_0, [172:344) c2_1
__global__ void k_c2(const float* __restrict__ time_b, const float* __restrict__ lin2_w,
                     const float* __restrict__ lin2_b, float* __restrict__ consts){
  int l = blockIdx.x, j = threadIdx.x;
  __shared__ float cb[DD];
  if (j < DD) cb[j] = cosf(time_b[j]);
  __syncthreads();
  if (j < DD){
    float acc = lin2_b[(size_t)l*DD + j];
    const float* W = lin2_w + (size_t)l*TK*DD;
    for (int d = 0; d < DD; d++) acc = fmaf(cb[d], W[(size_t)(2*DD + d)*DD + j], acc);
    consts[l*DD + j] = acc;
  }
}

// ---------------- hop-2 fused: nbr sums -> lin1 -> [h|src] -> lin2 -> emb1
// Transposed LDS staging: S[c][rr], H[c][rr] so the GEMM phases read all 8
// row-values of a column c with two broadcast ds_read_b128.
__global__ void k_hop2(const float* __restrict__ nf, const float* __restrict__ ef,
                       const float* __restrict__ mem, const float* __restrict__ tw,
                       const float* __restrict__ tb, const float* __restrict__ et,
                       const float* __restrict__ n2t, const int* __restrict__ n2i,
                       const int* __restrict__ n2e, const int* __restrict__ n1i,
                       const float* __restrict__ l1w, const float* __restrict__ l2w,
                       const float* __restrict__ l1b, const float* __restrict__ consts,
                       float* __restrict__ emb1){
  int t = threadIdx.x;
  int r0 = blockIdx.x * 8;                 // 1875*8 = 15000 exact
  __shared__ __align__(16) float S[TK][8];     // 16512 B
  __shared__ __align__(16) float H[2*DD][8];   // 11008 B
  __shared__ int   I2[8*KK], E2[8*KK], SID[8];
  __shared__ float T2[8*KK];
  if (t < 8*KK){
    int r = r0 + t/KK, k = t % KK;
    I2[t] = n2i[(size_t)r*KK + k];
    E2[t] = n2e[(size_t)r*KK + k];
    T2[t] = n2t[(size_t)r*KK + k];
  }
  if (t >= 96 && t < 104) SID[t-96] = n1i[r0 + (t-96)];
  __syncthreads();
  if (t < DD){
    float w = tw[t], b = tb[t];
    for (int rr = 0; rr < 8; rr++){
      int r = r0 + rr;
      float ts = et[(r/KK) % BB];          // ts1 = repeat(concat(et,et,et), K)
      float sn = 0.f, sd = 0.f, se = 0.f;
      #pragma unroll
      for (int k = 0; k < KK; k++){
        int id = I2[rr*KK + k];
        int e  = E2[rr*KK + k];
        float dt = ts - T2[rr*KK + k];
        sn += mem[(size_t)id*DD + t] + nf[(size_t)id*DD + t];
        sd += cosf(dt*w + b);
        se += ef[(size_t)e*DD + t];
      }
      S[t][rr] = sn; S[DD + t][rr] = sd; S[2*DD + t][rr] = se;
      int sid = SID[rr];                   // src of hop-2 row = flat nbr1_ids
      H[DD + t][rr] = mem[(size_t)sid*DD + t] + nf[(size_t)sid*DD + t];
    }
  }
  __syncthreads();
  if (t < DD){                             // h = relu(S @ W1_0 + 10*b1_0)
    float acc[8];
    float b10 = 10.f * l1b[t];
    #pragma unroll
    for (int rr = 0; rr < 8; rr++) acc[rr] = b10;
    const float* Wp = l1w + t;
    #pragma unroll 4
    for (int c = 0; c < TK; c++){
      float wv = Wp[(size_t)c*DD];
      float4 a = *reinterpret_cast<const float4*>(&S[c][0]);
      float4 q = *reinterpret_cast<const float4*>(&S[c][4]);
      acc[0] = fmaf(a.x, wv, acc[0]); acc[1] = fmaf(a.y, wv, acc[1]);
      acc[2] = fmaf(a.z, wv, acc[2]); acc[3] = fmaf(a.w, wv, acc[3]);
      acc[4] = fmaf(q.x, wv, acc[4]); acc[5] = fmaf(q.y, wv, acc[5]);
      acc[6] = fmaf(q.z, wv, acc[6]); acc[7] = fmaf(q.w, wv, acc[7]);
    }
    #pragma unroll
    for (int rr = 0; rr < 8; rr++) H[t][rr] = fmaxf(acc[rr], 0.f);
  }
  __syncthreads();
  if (t < DD){                             // emb1 = [h|src] @ W2_0[0:344] + c2_0
    float acc[8];
    float c2 = consts[t];
    #pragma unroll
    for (int rr = 0; rr < 8; rr++) acc[rr] = c2;
    const float* Wp = l2w + t;
    #pragma unroll 4
    for (int c = 0; c < 2*DD; c++){
      float wv = Wp[(size_t)c*DD];
      float4 a = *reinterpret_cast<const float4*>(&H[c][0]);
      float4 q = *reinterpret_cast<const float4*>(&H[c][4]);
      acc[0] = fmaf(a.x, wv, acc[0]); acc[1] = fmaf(a.y, wv, acc[1]);
      acc[2] = fmaf(a.z, wv, acc[2]); acc[3] = fmaf(a.w, wv, acc[3]);
      acc[4] = fmaf(q.x, wv, acc[4]); acc[5] = fmaf(q.y, wv, acc[5]);
      acc[6] = fmaf(q.z, wv, acc[6]); acc[7] = fmaf(q.w, wv, acc[7]);
    }
    #pragma unroll
    for (int rr = 0; rr < 8; rr++) emb1[(size_t)(r0+rr)*DD + t] = acc[rr];
  }
}

// ---------------- hop-1 fused: layer-1 weights, emb2 f32 ------------------
__global__ void k_hop1(const float* __restrict__ nf, const float* __restrict__ ef,
                       const float* __restrict__ mem, const float* __restrict__ tw,
                       const float* __restrict__ tb, const float* __restrict__ et,
                       const float* __restrict__ n1t, const int* __restrict__ n1e,
                       const int* __restrict__ src, const int* __restrict__ dst,
                       const int* __restrict__ neg, const float* __restrict__ emb1,
                       const float* __restrict__ l1w, const float* __restrict__ l2w,
                       const float* __restrict__ l1b, const float* __restrict__ consts,
                       float* __restrict__ emb2){
  int t = threadIdx.x;
  int r0 = blockIdx.x * 8;                 // 188 blocks; clamp reads, guard writes
  __shared__ __align__(16) float S[TK][8];
  __shared__ __align__(16) float H[2*DD][8];
  __shared__ int   E1[8*KK], SID[8];
  __shared__ float T1[8*KK];
  if (t < 8*KK){
    int q = r0 + t/KK; if (q >= NR1) q = NR1 - 1;
    int k = t % KK;
    E1[t] = n1e[(size_t)q*KK + k];
    T1[t] = n1t[(size_t)q*KK + k];
  }
  if (t >= 96 && t < 104){
    int q = r0 + (t - 96); if (q >= NR1) q = NR1 - 1;
    SID[t-96] = (q < BB) ? src[q] : (q < 2*BB ? dst[q - BB] : neg[q - 2*BB]);
  }
  __syncthreads();
  if (t < DD){
    float w = tw[t], b = tb[t];
    for (int rr = 0; rr < 8; rr++){
      int q = r0 + rr; if (q >= NR1) q = NR1 - 1;
      float ts = et[q % BB];
      float sn = 0.f, sd = 0.f, se = 0.f;
      #pragma unroll
      for (int k = 0; k < KK; k++){
        int e = E1[rr*KK + k];
        float dt = ts - T1[rr*KK + k];
        sn += emb1[((size_t)q*KK + k)*DD + t];
        sd += cosf(dt*w + b);
        se += ef[(size_t)e*DD + t];
      }
      S[t][rr] = sn; S[DD + t][rr] = sd; S[2*DD + t][rr] = se;
      int sid = SID[rr];
      H[DD + t][rr] = mem[(size_t)sid*DD + t] + nf[(size_t)sid*DD + t];
    }
  }
  __syncthreads();
  if (t < DD){
    float acc[8];
    float b10 = 10.f * l1b[t];
    #pragma unroll
    for (int rr = 0; rr < 8; rr++) acc[rr] = b10;
    const float* Wp = l1w + t;
    #pragma unroll 4
    for (int c = 0; c < TK; c++){
      float wv = Wp[(size_t)c*DD];
      float4 a = *reinterpret_cast<const float4*>(&S[c][0]);
      float4 q = *reinterpret_cast<const float4*>(&S[c][4]);
      acc[0] = fmaf(a.x, wv, acc[0]); acc[1] = fmaf(a.y, wv, acc[1]);
      acc[2] = fmaf(a.z, wv, acc[2]); acc[3] = fmaf(a.w, wv, acc[3]);
      acc[4] = fmaf(q.x, wv, acc[4]); acc[5] = fmaf(q.y, wv, acc[5]);
      acc[6] = fmaf(q.z, wv, acc[6]); acc[7] = fmaf(q.w, wv, acc[7]);
    }
    #pragma unroll
    for (int rr = 0; rr < 8; rr++) H[t][rr] = fmaxf(acc[rr], 0.f);
  }
  __syncthreads();
  if (t < DD){
    float acc[8];
    float c2 = consts[DD + t];
    #pragma unroll
    for (int rr = 0; rr < 8; rr++) acc[rr] = c2;
    const float* Wp = l2w + t;
    #pragma unroll 4
    for (int c = 0; c < 2*DD; c++){
      float wv = Wp[(size_t)c*DD];
      float4 a = *reinterpret_cast<const float4*>(&H[c][0]);
      float4 q = *reinterpret_cast<const float4*>(&H[c][4]);
      acc[0] = fmaf(a.x, wv, acc[0]); acc[1] = fmaf(a.y, wv, acc[1]);
      acc[2] = fmaf(a.z, wv, acc[2]); acc[3] = fmaf(a.w, wv, acc[3]);
      acc[4] = fmaf(q.x, wv, acc[4]); acc[5] = fmaf(q.y, wv, acc[5]);
      acc[6] = fmaf(q.z, wv, acc[6]); acc[7] = fmaf(q.w, wv, acc[7]);
    }
    #pragma unroll
    for (int rr = 0; rr < 8; rr++){
      int q = r0 + rr;
      if (q < NR1) emb2[(size_t)q*DD + t] = acc[rr];
    }
  }
}

// ---------------- affinity head -------------------------------------------
__global__ void k_merge(const float* __restrict__ emb2, const float* __restrict__ aff_w1,
                        const float* __restrict__ aff_b1, const float* __restrict__ aff_w2,
                        const float* __restrict__ aff_b2, float* __restrict__ out){
  int idx = blockIdx.x;            // 0..999: [0,500) pos, [500,1000) neg
  int which = idx / BB, r = idx % BB;
  int t = threadIdx.x;
  __shared__ float x1[DD], x2[DD], hs[DD];
  if (t < DD){
    x1[t] = emb2[(size_t)r*DD + t];
    x2[t] = emb2[(size_t)(which == 0 ? BB + r : 2*BB + r)*DD + t];
  }
  __syncthreads();
  if (t < DD){
    float acc = aff_b1[t];
    for (int c = 0; c < DD; c++) acc = fmaf(x1[c], aff_w1[(size_t)c*DD + t], acc);
    for (int c = 0; c < DD; c++) acc = fmaf(x2[c], aff_w1[(size_t)(DD + c)*DD + t], acc);
    hs[t] = fmaxf(acc, 0.f) * aff_w2[t];
  }
  __syncthreads();
  if (t < 64){
    float s = hs[t] + hs[t + 64];
    if (t < DD - 128) s += hs[t + 128];
    #pragma unroll
    for (int off = 32; off > 0; off >>= 1) s += __shfl_down(s, off, 64);
    if (t == 0) out[which*BB + r] = sigm(s + aff_b2[0]);
  }
}

// ---------------- decode: emb2[0:1000] @ dec_w + dec_b --------------------
__global__ void k_dec(const float* __restrict__ emb2, const float* __restrict__ dec_w,
                      const float* __restrict__ dec_b, float* __restrict__ out){
  int t = threadIdx.x;
  int r0 = blockIdx.x * 8;                 // 125*8 = 1000 exact
  if (t < DD){
    float acc[8];
    float bj = dec_b[t];
    #pragma unroll
    for (int rr = 0; rr < 8; rr++) acc[rr] = bj;
    for (int c = 0; c < DD; c++){
      float wv = dec_w[(size_t)c*DD + t];
      #pragma unroll
      for (int rr = 0; rr < 8; rr++)
        acc[rr] = fmaf(emb2[(size_t)(r0+rr)*DD + c], wv, acc[rr]);
    }
    #pragma unroll
    for (int rr = 0; rr < 8; rr++) out[(size_t)(r0+rr)*DD + t] = acc[rr];
  }
}

// ---------------- raw output: node_feats gather ---------------------------
__global__ void k_raw(const float* __restrict__ node_feats, const int* __restrict__ src,
                      const int* __restrict__ dst, float* __restrict__ out){
  int q = blockIdx.x, t = threadIdx.x;
  int id = (q < BB) ? src[q] : dst[q - BB];
  if (t < DD) out[(size_t)q*DD + t] = node_feats[(size_t)id*DD + t];
}

extern "C" void kernel_launch(void* const* d_in, const int* in_sizes, int n_in,
                              void* d_out, int out_size, void* d_ws, size_t ws_size,
                              hipStream_t stream){
  (void)in_sizes; (void)n_in; (void)out_size; (void)ws_size;
  const float* node_feats = (const float*)d_in[0];
  const float* edge_feats = (const float*)d_in[1];
  float*       memory     = (float*)d_in[2];      // updated in place (harness restores)
  const float* time_w     = (const float*)d_in[3];
  const float* time_b     = (const float*)d_in[4];
  const float* W_ih       = (const float*)d_in[5];
  const float* W_hh       = (const float*)d_in[6];
  const float* b_ih       = (const float*)d_in[7];
  const float* b_hh       = (const float*)d_in[8];
  const float* lin1_w     = (const float*)d_in[9];
  const float* lin1_b     = (const float*)d_in[10];
  const float* lin2_w     = (const float*)d_in[11];
  const float* lin2_b     = (const float*)d_in[12];
  const float* aff_w1     = (const float*)d_in[13];
  const float* aff_b1     = (const float*)d_in[14];
  const float* aff_w2     = (const float*)d_in[15];
  const float* aff_b2     = (const float*)d_in[16];
  const float* dec_w      = (const float*)d_in[17];
  const float* dec_b      = (const float*)d_in[18];
  const float* edge_times = (const float*)d_in[19];
  const float* nbr1_t     = (const float*)d_in[20];
  const float* nbr2_t     = (const float*)d_in[21];
  const float* msgs       = (const float*)d_in[22];
  const int* src        = (const int*)d_in[24];
  const int* dst        = (const int*)d_in[25];
  const int* neg        = (const int*)d_in[26];
  const int* nbr1_ids   = (const int*)d_in[28];
  const int* nbr1_eidx  = (const int*)d_in[29];
  const int* nbr2_ids   = (const int*)d_in[30];
  const int* nbr2_eidx  = (const int*)d_in[31];
  const int* msg_ids    = (const int*)d_in[32];
  float* out = (float*)d_out;

  // ws layout (~11.35 MB, identical footprint to last passing version):
  //   consts @ 0 (344 floats, padded to 2048 B), emb1 @ +2048 B, emb2 after.
  // Transposed GRU weights are TRANSIENT: aliased into the emb1 region
  // (k_tr -> k_gru2 finish before k_hop2 overwrites emb1; stream-ordered).
  float* consts = (float*)d_ws;                               // 344 floats
  float* emb1   = (float*)((char*)d_ws + 2048);               // 15000*172 f32
  float* emb2   = emb1 + (size_t)NR2*DD;                      // 1500*172 f32
  float* WT_ih  = emb1;                                       // [MSGW][TK] 355008 f32 (transient)
  float* WT_hh  = WT_ih + (size_t)MSGW*TK;                    // [DD][TK]    88752 f32 (transient)

  k_tr  <<<dim3((MSGW+31)/32, (TK+31)/32), dim3(32,8), 0, stream>>>(W_ih, WT_ih, TK, MSGW);
  k_tr  <<<dim3((DD+31)/32,   (TK+31)/32), dim3(32,8), 0, stream>>>(W_hh, WT_hh, TK, DD);
  k_gru2<<<MM/2, 192, 0, stream>>>(msgs, memory, WT_ih, WT_hh, b_ih, b_hh, msg_ids);
  k_c2  <<<2, 192, 0, stream>>>(time_b, lin2_w, lin2_b, consts);
  k_hop2<<<NR2/8, 192, 0, stream>>>(node_feats, edge_feats, memory, time_w, time_b,
                                    edge_times, nbr2_t, nbr2_ids, nbr2_eidx, nbr1_ids,
                                    lin1_w, lin2_w, lin1_b, consts, emb1);
  k_hop1<<<(NR1+7)/8, 192, 0, stream>>>(node_feats, edge_feats, memory, time_w, time_b,
                                        edge_times, nbr1_t, nbr1_eidx, src, dst, neg,
                                        emb1, lin1_w + (size_t)TK*DD, lin2_w + (size_t)TK*DD,
                                        lin1_b + DD, consts, emb2);
  k_merge<<<2*BB, 192, 0, stream>>>(emb2, aff_w1, aff_b1, aff_w2, aff_b2, out);
  k_dec <<<MM/8, 192, 0, stream>>>(emb2, dec_w, dec_b, out + 2*BB);
  k_raw <<<MM, 192, 0, stream>>>(node_feats, src, dst, out + 2*BB + (size_t)MM*DD);
}

// Round 3
// 938.513 us; speedup vs baseline: 1.1738x; 1.0588x over previous
//
#include <hip/hip_runtime.h>

#define DD   172
#define TK   516      // 3*D
#define BB   500
#define KK   10
#define MM   1000
#define MSGW 688
#define NR1  1500     // 3*B
#define NR2  15000    // 3*B*K

__device__ __forceinline__ float sigm(float x){ return 1.f / (1.f + expf(-x)); }

// ---------------- generic 32x32 tiled transpose: in[R][C] -> out[C][R] ----
__global__ void k_tr(const float* __restrict__ in, float* __restrict__ out,
                     int R, int C){
  __shared__ float tile[32][33];
  int c0 = blockIdx.x * 32, r0 = blockIdx.y * 32;
  int tx = threadIdx.x, ty = threadIdx.y;        // block 32x8
  for (int i = ty; i < 32; i += 8){
    int r = r0 + i, c = c0 + tx;
    if (r < R && c < C) tile[i][tx] = in[(size_t)r*C + c];
  }
  __syncthreads();
  for (int i = ty; i < 32; i += 8){
    int c = c0 + i, r = r0 + tx;
    if (c < C && r < R) out[(size_t)c*R + r] = tile[tx][i];
  }
}

// ---------------- GRU memory update, 2 msgs/block, transposed weights -----
// msg_node_ids = arange(1000): each block touches only its own rows.
__global__ void k_gru2(const float* __restrict__ msgs, float* memory,
                       const float* __restrict__ WT_ih,   // [MSGW][TK]
                       const float* __restrict__ WT_hh,   // [DD][TK]
                       const float* __restrict__ b_ih, const float* __restrict__ b_hh,
                       const int* __restrict__ ids){
  int t = threadIdx.x;
  int r0 = blockIdx.x * 2;                // 500 blocks
  __shared__ __align__(16) float xT[MSGW][2];
  __shared__ __align__(16) float hT[DD][2];
  int s0 = ids[r0], s1 = ids[r0 + 1];
  for (int c = t; c < MSGW; c += 192){
    xT[c][0] = msgs[(size_t)r0*MSGW + c];
    xT[c][1] = msgs[(size_t)(r0+1)*MSGW + c];
  }
  if (t < DD){
    hT[t][0] = memory[(size_t)s0*DD + t];
    hT[t][1] = memory[(size_t)s1*DD + t];
  }
  __syncthreads();
  if (t < DD){
    float gi00 = b_ih[t],      gi01 = gi00;
    float gi10 = b_ih[DD+t],   gi11 = gi10;
    float gi20 = b_ih[2*DD+t], gi21 = gi20;
    for (int c0 = 0; c0 < MSGW; c0 += 8){       // 86*8 = 688 exact
      float w0[8], w1[8], w2[8]; float2 xv[8];
      #pragma unroll
      for (int u = 0; u < 8; u++){
        const float* wr = WT_ih + (size_t)(c0+u)*TK;
        w0[u] = wr[t]; w1[u] = wr[DD+t]; w2[u] = wr[2*DD+t];
        xv[u] = *reinterpret_cast<const float2*>(&xT[c0+u][0]);
      }
      #pragma unroll
      for (int u = 0; u < 8; u++){
        gi00 = fmaf(xv[u].x, w0[u], gi00); gi01 = fmaf(xv[u].y, w0[u], gi01);
        gi10 = fmaf(xv[u].x, w1[u], gi10); gi11 = fmaf(xv[u].y, w1[u], gi11);
        gi20 = fmaf(xv[u].x, w2[u], gi20); gi21 = fmaf(xv[u].y, w2[u], gi21);
      }
    }
    float gh00 = b_hh[t],      gh01 = gh00;
    float gh10 = b_hh[DD+t],   gh11 = gh10;
    float gh20 = b_hh[2*DD+t], gh21 = gh20;
    for (int c0 = 0; c0 < DD; c0 += 4){         // 43*4 = 172 exact
      float w0[4], w1[4], w2[4]; float2 hv[4];
      #pragma unroll
      for (int u = 0; u < 4; u++){
        const float* wr = WT_hh + (size_t)(c0+u)*TK;
        w0[u] = wr[t]; w1[u] = wr[DD+t]; w2[u] = wr[2*DD+t];
        hv[u] = *reinterpret_cast<const float2*>(&hT[c0+u][0]);
      }
      #pragma unroll
      for (int u = 0; u < 4; u++){
        gh00 = fmaf(hv[u].x, w0[u], gh00); gh01 = fmaf(hv[u].y, w0[u], gh01);
        gh10 = fmaf(hv[u].x, w1[u], gh10); gh11 = fmaf(hv[u].y, w1[u], gh11);
        gh20 = fmaf(hv[u].x, w2[u], gh20); gh21 = fmaf(hv[u].y, w2[u], gh21);
      }
    }
    {
      float r_ = sigm(gi00 + gh00);
      float z  = sigm(gi10 + gh10);
      float g  = tanhf(gi20 + r_*gh20);
      memory[(size_t)s0*DD + t] = (1.f - z)*g + z*hT[t][0];
    }
    {
      float r_ = sigm(gi01 + gh01);
      float z  = sigm(gi11 + gh11);
      float g  = tanhf(gi21 + r_*gh21);
      memory[(size_t)s1*DD + t] = (1.f - z)*g + z*hT[t][1];
    }
  }
}

// ---------------- lin2 "st" constant: c2_l[j] = b2_l[j] + sum_d cos(b_d) W2_l[2D+d][j]
// consts layout: [0:172) c2_0, [172:344) c2_1
__global__ void k_c2(const float* __restrict__ time_b, const float* __restrict__ lin2_w,
                     const float* __restrict__ lin2_b, float* __restrict__ consts){
  int l = blockIdx.x, j = threadIdx.x;
  __shared__ float cb[DD];
  if (j < DD) cb[j] = cosf(time_b[j]);
  __syncthreads();
  if (j < DD){
    float acc = lin2_b[(size_t)l*DD + j];
    const float* W = lin2_w + (size_t)l*TK*DD + (size_t)2*DD*DD + j;
    for (int d0 = 0; d0 < DD; d0 += 4){         // 43*4 = 172 exact
      float wv[4];
      #pragma unroll
      for (int u = 0; u < 4; u++) wv[u] = W[(size_t)(d0+u)*DD];
      #pragma unroll
      for (int u = 0; u < 4; u++) acc = fmaf(cb[d0+u], wv[u], acc);
    }
    consts[l*DD + j] = acc;
  }
}

// ---------------- hop-2 fused: nbr sums -> lin1 -> [h|src] -> lin2 -> emb1
// Transposed LDS staging (S[c][rr]) with 30-deep gather pipelining; relu-h
// aliases S[0:DD] after S is fully consumed (extra barrier) to cut LDS to
// ~23 KB -> 7 blocks/CU.
__global__ void k_hop2(const float* __restrict__ nf, const float* __restrict__ ef,
                       const float* __restrict__ mem, const float* __restrict__ tw,
                       const float* __restrict__ tb, const float* __restrict__ et,
                       const float* __restrict__ n2t, const int* __restrict__ n2i,
                       const int* __restrict__ n2e, const int* __restrict__ n1i,
                       const float* __restrict__ l1w, const float* __restrict__ l2w,
                       const float* __restrict__ l1b, const float* __restrict__ consts,
                       float* __restrict__ emb1){
  int t = threadIdx.x;
  int r0 = blockIdx.x * 8;                 // 1875*8 = 15000 exact
  __shared__ __align__(16) float S[TK][8];     // 16512 B; [0:DD] reused as relu-h
  __shared__ __align__(16) float Hhi[DD][8];   // 5504 B: src-feat rows
  __shared__ int   I2[8*KK], E2[8*KK], SID[8];
  __shared__ float T2[8*KK];
  if (t < 8*KK){
    int r = r0 + t/KK, k = t % KK;
    I2[t] = n2i[(size_t)r*KK + k];
    E2[t] = n2e[(size_t)r*KK + k];
    T2[t] = n2t[(size_t)r*KK + k];
  }
  if (t >= 96 && t < 104) SID[t-96] = n1i[r0 + (t-96)];
  __syncthreads();
  if (t < DD){
    float w = tw[t], b = tb[t];
    for (int rr = 0; rr < 8; rr++){
      int r = r0 + rr;
      float ts = et[(r/KK) % BB];          // ts1 = repeat(concat(et,et,et), K)
      float vm[KK], vn[KK], ve[KK], vt[KK];
      #pragma unroll
      for (int k = 0; k < KK; k++){
        int id = I2[rr*KK + k];
        int e  = E2[rr*KK + k];
        vm[k] = mem[(size_t)id*DD + t];
        vn[k] = nf[(size_t)id*DD + t];
        ve[k] = ef[(size_t)e*DD + t];
        vt[k] = T2[rr*KK + k];
      }
      float sn = 0.f, sd = 0.f, se = 0.f;
      #pragma unroll
      for (int k = 0; k < KK; k++){
        sn += vm[k] + vn[k];
        sd += cosf((ts - vt[k])*w + b);
        se += ve[k];
      }
      S[t][rr] = sn; S[DD + t][rr] = sd; S[2*DD + t][rr] = se;
      int sid = SID[rr];                   // src of hop-2 row = flat nbr1_ids
      Hhi[t][rr] = mem[(size_t)sid*DD + t] + nf[(size_t)sid*DD + t];
    }
  }
  __syncthreads();
  float acc[8];
  if (t < DD){                             // h = relu(S @ W1_0 + 10*b1_0)
    float b10 = 10.f * l1b[t];
    #pragma unroll
    for (int rr = 0; rr < 8; rr++) acc[rr] = b10;
    const float* Wp = l1w + t;
    for (int c0 = 0; c0 < TK; c0 += 4){    // 129*4 = 516 exact
      float wv[4]; float4 a[4], q[4];
      #pragma unroll
      for (int u = 0; u < 4; u++){
        wv[u] = Wp[(size_t)(c0+u)*DD];
        a[u] = *reinterpret_cast<const float4*>(&S[c0+u][0]);
        q[u] = *reinterpret_cast<const float4*>(&S[c0+u][4]);
      }
      #pragma unroll
      for (int u = 0; u < 4; u++){
        acc[0]=fmaf(a[u].x,wv[u],acc[0]); acc[1]=fmaf(a[u].y,wv[u],acc[1]);
        acc[2]=fmaf(a[u].z,wv[u],acc[2]); acc[3]=fmaf(a[u].w,wv[u],acc[3]);
        acc[4]=fmaf(q[u].x,wv[u],acc[4]); acc[5]=fmaf(q[u].y,wv[u],acc[5]);
        acc[6]=fmaf(q[u].z,wv[u],acc[6]); acc[7]=fmaf(q[u].w,wv[u],acc[7]);
      }
    }
  }
  __syncthreads();                         // all S reads done before aliasing
  if (t < DD){
    float4 h0, h1;
    h0.x=fmaxf(acc[0],0.f); h0.y=fmaxf(acc[1],0.f); h0.z=fmaxf(acc[2],0.f); h0.w=fmaxf(acc[3],0.f);
    h1.x=fmaxf(acc[4],0.f); h1.y=fmaxf(acc[5],0.f); h1.z=fmaxf(acc[6],0.f); h1.w=fmaxf(acc[7],0.f);
    *reinterpret_cast<float4*>(&S[t][0]) = h0;
    *reinterpret_cast<float4*>(&S[t][4]) = h1;
  }
  __syncthreads();
  if (t < DD){                             // emb1 = [h|src] @ W2_0[0:344] + c2_0
    float c2 = consts[t];
    #pragma unroll
    for (int rr = 0; rr < 8; rr++) acc[rr] = c2;
    const float* Wp = l2w + t;
    for (int c0 = 0; c0 < DD; c0 += 4){    // h part (aliased into S[0:DD])
      float wv[4]; float4 a[4], q[4];
      #pragma unroll
      for (int u = 0; u < 4; u++){
        wv[u] = Wp[(size_t)(c0+u)*DD];
        a[u] = *reinterpret_cast<const float4*>(&S[c0+u][0]);
        q[u] = *reinterpret_cast<const float4*>(&S[c0+u][4]);
      }
      #pragma unroll
      for (int u = 0; u < 4; u++){
        acc[0]=fmaf(a[u].x,wv[u],acc[0]); acc[1]=fmaf(a[u].y,wv[u],acc[1]);
        acc[2]=fmaf(a[u].z,wv[u],acc[2]); acc[3]=fmaf(a[u].w,wv[u],acc[3]);
        acc[4]=fmaf(q[u].x,wv[u],acc[4]); acc[5]=fmaf(q[u].y,wv[u],acc[5]);
        acc[6]=fmaf(q[u].z,wv[u],acc[6]); acc[7]=fmaf(q[u].w,wv[u],acc[7]);
      }
    }
    for (int c0 = 0; c0 < DD; c0 += 4){    // src part (Hhi), weights offset DD
      float wv[4]; float4 a[4], q[4];
      #pragma unroll
      for (int u = 0; u < 4; u++){
        wv[u] = Wp[(size_t)(DD+c0+u)*DD];
        a[u] = *reinterpret_cast<const float4*>(&Hhi[c0+u][0]);
        q[u] = *reinterpret_cast<const float4*>(&Hhi[c0+u][4]);
      }
      #pragma unroll
      for (int u = 0; u < 4; u++){
        acc[0]=fmaf(a[u].x,wv[u],acc[0]); acc[1]=fmaf(a[u].y,wv[u],acc[1]);
        acc[2]=fmaf(a[u].z,wv[u],acc[2]); acc[3]=fmaf(a[u].w,wv[u],acc[3]);
        acc[4]=fmaf(q[u].x,wv[u],acc[4]); acc[5]=fmaf(q[u].y,wv[u],acc[5]);
        acc[6]=fmaf(q[u].z,wv[u],acc[6]); acc[7]=fmaf(q[u].w,wv[u],acc[7]);
      }
    }
    #pragma unroll
    for (int rr = 0; rr < 8; rr++) emb1[(size_t)(r0+rr)*DD + t] = acc[rr];
  }
}

// ---------------- hop-1 fused: layer-1 weights, emb2 f32 ------------------
__global__ void k_hop1(const float* __restrict__ nf, const float* __restrict__ ef,
                       const float* __restrict__ mem, const float* __restrict__ tw,
                       const float* __restrict__ tb, const float* __restrict__ et,
                       const float* __restrict__ n1t, const int* __restrict__ n1e,
                       const int* __restrict__ src, const int* __restrict__ dst,
                       const int* __restrict__ neg, const float* __restrict__ emb1,
                       const float* __restrict__ l1w, const float* __restrict__ l2w,
                       const float* __restrict__ l1b, const float* __restrict__ consts,
                       float* __restrict__ emb2){
  int t = threadIdx.x;
  int r0 = blockIdx.x * 8;                 // 188 blocks; clamp reads, guard writes
  __shared__ __align__(16) float S[TK][8];
  __shared__ __align__(16) float Hhi[DD][8];
  __shared__ int   E1[8*KK], SID[8];
  __shared__ float T1[8*KK];
  if (t < 8*KK){
    int q = r0 + t/KK; if (q >= NR1) q = NR1 - 1;
    int k = t % KK;
    E1[t] = n1e[(size_t)q*KK + k];
    T1[t] = n1t[(size_t)q*KK + k];
  }
  if (t >= 96 && t < 104){
    int q = r0 + (t - 96); if (q >= NR1) q = NR1 - 1;
    SID[t-96] = (q < BB) ? src[q] : (q < 2*BB ? dst[q - BB] : neg[q - 2*BB]);
  }
  __syncthreads();
  if (t < DD){
    float w = tw[t], b = tb[t];
    for (int rr = 0; rr < 8; rr++){
      int q = r0 + rr; if (q >= NR1) q = NR1 - 1;
      float ts = et[q % BB];
      float v1[KK], ve[KK], vt[KK];
      #pragma unroll
      for (int k = 0; k < KK; k++){
        int e = E1[rr*KK + k];
        v1[k] = emb1[((size_t)q*KK + k)*DD + t];
        ve[k] = ef[(size_t)e*DD + t];
        vt[k] = T1[rr*KK + k];
      }
      float sn = 0.f, sd = 0.f, se = 0.f;
      #pragma unroll
      for (int k = 0; k < KK; k++){
        sn += v1[k];
        sd += cosf((ts - vt[k])*w + b);
        se += ve[k];
      }
      S[t][rr] = sn; S[DD + t][rr] = sd; S[2*DD + t][rr] = se;
      int sid = SID[rr];
      Hhi[t][rr] = mem[(size_t)sid*DD + t] + nf[(size_t)sid*DD + t];
    }
  }
  __syncthreads();
  float acc[8];
  if (t < DD){
    float b10 = 10.f * l1b[t];
    #pragma unroll
    for (int rr = 0; rr < 8; rr++) acc[rr] = b10;
    const float* Wp = l1w + t;
    for (int c0 = 0; c0 < TK; c0 += 4){
      float wv[4]; float4 a[4], q[4];
      #pragma unroll
      for (int u = 0; u < 4; u++){
        wv[u] = Wp[(size_t)(c0+u)*DD];
        a[u] = *reinterpret_cast<const float4*>(&S[c0+u][0]);
        q[u] = *reinterpret_cast<const float4*>(&S[c0+u][4]);
      }
      #pragma unroll
      for (int u = 0; u < 4; u++){
        acc[0]=fmaf(a[u].x,wv[u],acc[0]); acc[1]=fmaf(a[u].y,wv[u],acc[1]);
        acc[2]=fmaf(a[u].z,wv[u],acc[2]); acc[3]=fmaf(a[u].w,wv[u],acc[3]);
        acc[4]=fmaf(q[u].x,wv[u],acc[4]); acc[5]=fmaf(q[u].y,wv[u],acc[5]);
        acc[6]=fmaf(q[u].z,wv[u],acc[6]); acc[7]=fmaf(q[u].w,wv[u],acc[7]);
      }
    }
  }
  __syncthreads();
  if (t < DD){
    float4 h0, h1;
    h0.x=fmaxf(acc[0],0.f); h0.y=fmaxf(acc[1],0.f); h0.z=fmaxf(acc[2],0.f); h0.w=fmaxf(acc[3],0.f);
    h1.x=fmaxf(acc[4],0.f); h1.y=fmaxf(acc[5],0.f); h1.z=fmaxf(acc[6],0.f); h1.w=fmaxf(acc[7],0.f);
    *reinterpret_cast<float4*>(&S[t][0]) = h0;
    *reinterpret_cast<float4*>(&S[t][4]) = h1;
  }
  __syncthreads();
  if (t < DD){
    float c2 = consts[DD + t];
    #pragma unroll
    for (int rr = 0; rr < 8; rr++) acc[rr] = c2;
    const float* Wp = l2w + t;
    for (int c0 = 0; c0 < DD; c0 += 4){
      float wv[4]; float4 a[4], q[4];
      #pragma unroll
      for (int u = 0; u < 4; u++){
        wv[u] = Wp[(size_t)(c0+u)*DD];
        a[u] = *reinterpret_cast<const float4*>(&S[c0+u][0]);
        q[u] = *reinterpret_cast<const float4*>(&S[c0+u][4]);
      }
      #pragma unroll
      for (int u = 0; u < 4; u++){
        acc[0]=fmaf(a[u].x,wv[u],acc[0]); acc[1]=fmaf(a[u].y,wv[u],acc[1]);
        acc[2]=fmaf(a[u].z,wv[u],acc[2]); acc[3]=fmaf(a[u].w,wv[u],acc[3]);
        acc[4]=fmaf(q[u].x,wv[u],acc[4]); acc[5]=fmaf(q[u].y,wv[u],acc[5]);
        acc[6]=fmaf(q[u].z,wv[u],acc[6]); acc[7]=fmaf(q[u].w,wv[u],acc[7]);
      }
    }
    for (int c0 = 0; c0 < DD; c0 += 4){
      float wv[4]; float4 a[4], q[4];
      #pragma unroll
      for (int u = 0; u < 4; u++){
        wv[u] = Wp[(size_t)(DD+c0+u)*DD];
        a[u] = *reinterpret_cast<const float4*>(&Hhi[c0+u][0]);
        q[u] = *reinterpret_cast<const float4*>(&Hhi[c0+u][4]);
      }
      #pragma unroll
      for (int u = 0; u < 4; u++){
        acc[0]=fmaf(a[u].x,wv[u],acc[0]); acc[1]=fmaf(a[u].y,wv[u],acc[1]);
        acc[2]=fmaf(a[u].z,wv[u],acc[2]); acc[3]=fmaf(a[u].w,wv[u],acc[3]);
        acc[4]=fmaf(q[u].x,wv[u],acc[4]); acc[5]=fmaf(q[u].y,wv[u],acc[5]);
        acc[6]=fmaf(q[u].z,wv[u],acc[6]); acc[7]=fmaf(q[u].w,wv[u],acc[7]);
      }
    }
    #pragma unroll
    for (int rr = 0; rr < 8; rr++){
      int q = r0 + rr;
      if (q < NR1) emb2[(size_t)q*DD + t] = acc[rr];
    }
  }
}

// ---------------- affinity head -------------------------------------------
__global__ void k_merge(const float* __restrict__ emb2, const float* __restrict__ aff_w1,
                        const float* __restrict__ aff_b1, const float* __restrict__ aff_w2,
                        const float* __restrict__ aff_b2, float* __restrict__ out){
  int idx = blockIdx.x;            // 0..999: [0,500) pos, [500,1000) neg
  int which = idx / BB, r = idx % BB;
  int t = threadIdx.x;
  __shared__ float x1[DD], x2[DD], hs[DD];
  if (t < DD){
    x1[t] = emb2[(size_t)r*DD + t];
    x2[t] = emb2[(size_t)(which == 0 ? BB + r : 2*BB + r)*DD + t];
  }
  __syncthreads();
  if (t < DD){
    float acc = aff_b1[t];
    const float* W1 = aff_w1 + t;
    for (int c0 = 0; c0 < DD; c0 += 4){
      float wv[4];
      #pragma unroll
      for (int u = 0; u < 4; u++) wv[u] = W1[(size_t)(c0+u)*DD];
      #pragma unroll
      for (int u = 0; u < 4; u++) acc = fmaf(x1[c0+u], wv[u], acc);
    }
    for (int c0 = 0; c0 < DD; c0 += 4){
      float wv[4];
      #pragma unroll
      for (int u = 0; u < 4; u++) wv[u] = W1[(size_t)(DD+c0+u)*DD];
      #pragma unroll
      for (int u = 0; u < 4; u++) acc = fmaf(x2[c0+u], wv[u], acc);
    }
    hs[t] = fmaxf(acc, 0.f) * aff_w2[t];
  }
  __syncthreads();
  if (t < 64){
    float s = hs[t] + hs[t + 64];
    if (t < DD - 128) s += hs[t + 128];
    #pragma unroll
    for (int off = 32; off > 0; off >>= 1) s += __shfl_down(s, off, 64);
    if (t == 0) out[which*BB + r] = sigm(s + aff_b2[0]);
  }
}

// ---------------- decode: emb2[0:1000] @ dec_w + dec_b --------------------
__global__ void k_dec(const float* __restrict__ emb2, const float* __restrict__ dec_w,
                      const float* __restrict__ dec_b, float* __restrict__ out){
  int t = threadIdx.x;
  int r0 = blockIdx.x * 8;                 // 125*8 = 1000 exact
  __shared__ __align__(16) float E[8*DD];  // 8 emb2 rows (contiguous)
  for (int i = t; i < 8*DD; i += 192) E[i] = emb2[(size_t)r0*DD + i];
  __syncthreads();
  if (t < DD){
    float acc[8];
    float bj = dec_b[t];
    #pragma unroll
    for (int rr = 0; rr < 8; rr++) acc[rr] = bj;
    const float* Wp = dec_w + t;
    for (int c0 = 0; c0 < DD; c0 += 4){
      float wv[4];
      #pragma unroll
      for (int u = 0; u < 4; u++) wv[u] = Wp[(size_t)(c0+u)*DD];
      #pragma unroll
      for (int u = 0; u < 4; u++){
        #pragma unroll
        for (int rr = 0; rr < 8; rr++)
          acc[rr] = fmaf(E[rr*DD + c0+u], wv[u], acc[rr]);
      }
    }
    #pragma unroll
    for (int rr = 0; rr < 8; rr++) out[(size_t)(r0+rr)*DD + t] = acc[rr];
  }
}

// ---------------- raw output: node_feats gather ---------------------------
__global__ void k_raw(const float* __restrict__ node_feats, const int* __restrict__ src,
                      const int* __restrict__ dst, float* __restrict__ out){
  int q = blockIdx.x, t = threadIdx.x;
  int id = (q < BB) ? src[q] : dst[q - BB];
  if (t < DD) out[(size_t)q*DD + t] = node_feats[(size_t)id*DD + t];
}

extern "C" void kernel_launch(void* const* d_in, const int* in_sizes, int n_in,
                              void* d_out, int out_size, void* d_ws, size_t ws_size,
                              hipStream_t stream){
  (void)in_sizes; (void)n_in; (void)out_size; (void)ws_size;
  const float* node_feats = (const float*)d_in[0];
  const float* edge_feats = (const float*)d_in[1];
  float*       memory     = (float*)d_in[2];      // updated in place (harness restores)
  const float* time_w     = (const float*)d_in[3];
  const float* time_b     = (const float*)d_in[4];
  const float* W_ih       = (const float*)d_in[5];
  const float* W_hh       = (const float*)d_in[6];
  const float* b_ih       = (const float*)d_in[7];
  const float* b_hh       = (const float*)d_in[8];
  const float* lin1_w     = (const float*)d_in[9];
  const float* lin1_b     = (const float*)d_in[10];
  const float* lin2_w     = (const float*)d_in[11];
  const float* lin2_b     = (const float*)d_in[12];
  const float* aff_w1     = (const float*)d_in[13];
  const float* aff_b1     = (const float*)d_in[14];
  const float* aff_w2     = (const float*)d_in[15];
  const float* aff_b2     = (const float*)d_in[16];
  const float* dec_w      = (const float*)d_in[17];
  const float* dec_b      = (const float*)d_in[18];
  const float* edge_times = (const float*)d_in[19];
  const float* nbr1_t     = (const float*)d_in[20];
  const float* nbr2_t     = (const float*)d_in[21];
  const float* msgs       = (const float*)d_in[22];
  const int* src        = (const int*)d_in[24];
  const int* dst        = (const int*)d_in[25];
  const int* neg        = (const int*)d_in[26];
  const int* nbr1_ids   = (const int*)d_in[28];
  const int* nbr1_eidx  = (const int*)d_in[29];
  const int* nbr2_ids   = (const int*)d_in[30];
  const int* nbr2_eidx  = (const int*)d_in[31];
  const int* msg_ids    = (const int*)d_in[32];
  float* out = (float*)d_out;

  // ws layout (~11.35 MB, identical footprint to last passing version):
  //   consts @ 0 (344 floats, padded to 2048 B), emb1 @ +2048 B, emb2 after.
  // Transposed GRU weights are TRANSIENT: aliased into the emb1 region
  // (k_tr -> k_gru2 finish before k_hop2 overwrites emb1; stream-ordered).
  float* consts = (float*)d_ws;                               // 344 floats
  float* emb1   = (float*)((char*)d_ws + 2048);               // 15000*172 f32
  float* emb2   = emb1 + (size_t)NR2*DD;                      // 1500*172 f32
  float* WT_ih  = emb1;                                       // [MSGW][TK] 355008 f32 (transient)
  float* WT_hh  = WT_ih + (size_t)MSGW*TK;                    // [DD][TK]    88752 f32 (transient)

  k_tr  <<<dim3((MSGW+31)/32, (TK+31)/32), dim3(32,8), 0, stream>>>(W_ih, WT_ih, TK, MSGW);
  k_tr  <<<dim3((DD+31)/32,   (TK+31)/32), dim3(32,8), 0, stream>>>(W_hh, WT_hh, TK, DD);
  k_gru2<<<MM/2, 192, 0, stream>>>(msgs, memory, WT_ih, WT_hh, b_ih, b_hh, msg_ids);
  k_c2  <<<2, 192, 0, stream>>>(time_b, lin2_w, lin2_b, consts);
  k_hop2<<<NR2/8, 192, 0, stream>>>(node_feats, edge_feats, memory, time_w, time_b,
                                    edge_times, nbr2_t, nbr2_ids, nbr2_eidx, nbr1_ids,
                                    lin1_w, lin2_w, lin1_b, consts, emb1);
  k_hop1<<<(NR1+7)/8, 192, 0, stream>>>(node_feats, edge_feats, memory, time_w, time_b,
                                        edge_times, nbr1_t, nbr1_eidx, src, dst, neg,
                                        emb1, lin1_w + (size_t)TK*DD, lin2_w + (size_t)TK*DD,
                                        lin1_b + DD, consts, emb2);
  k_merge<<<2*BB, 192, 0, stream>>>(emb2, aff_w1, aff_b1, aff_w2, aff_b2, out);
  k_dec <<<MM/8, 192, 0, stream>>>(emb2, dec_w, dec_b, out + 2*BB);
  k_raw <<<MM, 192, 0, stream>>>(node_feats, src, dst, out + 2*BB + (size_t)MM*DD);
}